// Round 1
// baseline (489.064 us; speedup 1.0000x reference)
//
#include <hip/hip_runtime.h>

// Problem constants: h (8,256,128), e (8,256,256,128), all fp32.
#define BB 8
#define NN 256
#define DD 128
#define NROWS ((long)BB * NN * NN)      // 524288 rows of 128 floats in e
#define NBI   (BB * NN)                 // 2048 (b,i) pairs / BN rows

// ---------------------------------------------------------------------------
// K1: w[r] = ||e[r,:]||_2 over d=128, and copy e -> out_e.  The only
// HBM-heavy kernel: 256 MB read + 256 MB write. 32 lanes per row, float4.
// ---------------------------------------------------------------------------
__global__ __launch_bounds__(256) void k_norm_copy(const float4* __restrict__ e,
                                                   float4* __restrict__ eo,
                                                   float* __restrict__ w) {
    const int tid  = threadIdx.x;
    const int q    = tid & 31;   // quarter-row slot (32 x float4 = 128 floats)
    const int rsub = tid >> 5;   // 0..7: row within block-iteration
    for (long base = (long)blockIdx.x * 8; base < NROWS; base += (long)gridDim.x * 8) {
        const long r   = base + rsub;
        const long idx = r * 32 + q;
        float4 v = e[idx];
        eo[idx] = v;
        float s = v.x * v.x + v.y * v.y + v.z * v.z + v.w * v.w;
        // reduce across the 32 lanes of this row (xor masks 1..16 stay
        // within each 32-lane half of the 64-lane wave)
        #pragma unroll
        for (int m = 16; m >= 1; m >>= 1) s += __shfl_xor(s, m, 64);
        if (q == 0) w[r] = sqrtf(s);
    }
}

// ---------------------------------------------------------------------------
// K2: per (b,i): softmax over j of w[b,i,:], agg = sum_j p[j]*h[b,j,:],
// x = h[b,i,:] + agg.  One 256-thread block per (b,i). h is 1 MB -> L2.
// ---------------------------------------------------------------------------
__global__ __launch_bounds__(256) void k_softmax_agg(const float* __restrict__ w,
                                                     const float* __restrict__ h,
                                                     float* __restrict__ x) {
    const int bi  = blockIdx.x;      // b*N + i
    const int b   = bi >> 8;
    const int tid = threadIdx.x;
    __shared__ float p[NN];
    __shared__ float red[8];
    __shared__ float acc2[DD];

    float v = w[(long)bi * NN + tid];
    // block max
    float m = v;
    #pragma unroll
    for (int msk = 32; msk >= 1; msk >>= 1) m = fmaxf(m, __shfl_xor(m, msk, 64));
    const int wid = tid >> 6, lane = tid & 63;
    if (lane == 0) red[wid] = m;
    __syncthreads();
    m = fmaxf(fmaxf(red[0], red[1]), fmaxf(red[2], red[3]));
    float ev = __expf(v - m);
    // block sum
    float s = ev;
    #pragma unroll
    for (int msk = 32; msk >= 1; msk >>= 1) s += __shfl_xor(s, msk, 64);
    if (lane == 0) red[4 + wid] = s;
    __syncthreads();
    s = (red[4] + red[5]) + (red[6] + red[7]);
    p[tid] = ev / s;
    __syncthreads();

    // agg: threads split j-range in half; thread handles feature d = tid&127
    const int d  = tid & 127;
    const int j0 = (tid >> 7) << 7;          // 0 or 128
    const float* hb = h + ((long)b * NN + j0) * DD + d;
    float acc = 0.f;
    #pragma unroll 8
    for (int j = 0; j < 128; ++j) acc += p[j0 + j] * hb[(long)j * DD];
    if (tid >= 128) acc2[d] = acc;
    __syncthreads();
    if (tid < 128) {
        const long o = (long)bi * DD + d;
        x[o] = h[o] + acc + acc2[d];
    }
}

// ---------------------------------------------------------------------------
// K3: y[row,k] = relu( sum_d x[row,d] * W[k,d] + bias[k] ).  One 128-thread
// block per row; x row staged in LDS; W (64 KB) L2-resident.
// ---------------------------------------------------------------------------
__global__ __launch_bounds__(128) void k_linear(const float* __restrict__ x,
                                                const float* __restrict__ W,
                                                const float* __restrict__ bias,
                                                float* __restrict__ y) {
    const int row = blockIdx.x;
    const int k   = threadIdx.x;
    __shared__ float xs[DD];
    xs[k] = x[(long)row * DD + k];
    __syncthreads();
    const float* wr = W + (long)k * DD;
    float acc = bias[k];
    #pragma unroll 4
    for (int d = 0; d < DD; ++d) acc += xs[d] * wr[d];
    acc = fmaxf(acc, 0.f);
    y[(long)row * DD + k] = acc;
}

// ---------------------------------------------------------------------------
// K4: BN batch stats, deterministic (no atomics, no ws zero-init needed).
// One block per feature k: sum and sumsq over 2048 rows.
// ---------------------------------------------------------------------------
__global__ __launch_bounds__(256) void k_stats(const float* __restrict__ y,
                                               float* __restrict__ sums) {
    const int k = blockIdx.x;
    const int t = threadIdx.x;
    float s = 0.f, s2 = 0.f;
    for (int r = t; r < NBI; r += 256) {
        float v = y[(long)r * DD + k];
        s += v; s2 += v * v;
    }
    __shared__ float ls[256], ls2[256];
    ls[t] = s; ls2[t] = s2;
    __syncthreads();
    for (int off = 128; off >= 1; off >>= 1) {
        if (t < off) { ls[t] += ls[t + off]; ls2[t] += ls2[t + off]; }
        __syncthreads();
    }
    if (t == 0) { sums[k] = ls[0]; sums[DD + k] = ls2[0]; }
}

// ---------------------------------------------------------------------------
// K5: out = (y - mean) * rsqrt(var + eps) * gamma + beta + h
// ---------------------------------------------------------------------------
__global__ __launch_bounds__(256) void k_bn(const float* __restrict__ y,
                                            const float* __restrict__ h,
                                            const float* __restrict__ sums,
                                            const float* __restrict__ gamma,
                                            const float* __restrict__ beta,
                                            float* __restrict__ out) {
    const long i = (long)blockIdx.x * blockDim.x + threadIdx.x;
    if (i >= (long)NBI * DD) return;
    const int k = (int)(i & (DD - 1));
    const float inv_n = 1.f / (float)NBI;
    float mean = sums[k] * inv_n;
    float var  = sums[DD + k] * inv_n - mean * mean;
    float inv  = rsqrtf(var + 1e-5f);
    out[i] = (y[i] - mean) * inv * gamma[k] + beta[k] + h[i];
}

extern "C" void kernel_launch(void* const* d_in, const int* in_sizes, int n_in,
                              void* d_out, int out_size, void* d_ws, size_t ws_size,
                              hipStream_t stream) {
    const float* h     = (const float*)d_in[0];
    const float* e     = (const float*)d_in[1];
    const float* W     = (const float*)d_in[2];
    const float* bias  = (const float*)d_in[3];
    const float* gamma = (const float*)d_in[4];
    const float* beta  = (const float*)d_in[5];

    float* out_h = (float*)d_out;                       // (8,256,128)
    float* out_e = out_h + (long)NBI * DD;              // (8,256,256,128) copy

    float* ws   = (float*)d_ws;
    float* w    = ws;                    // 524288 floats: ||e|| rows
    float* x    = ws + 524288;           // 262144: h + agg
    float* y    = ws + 786432;           // 262144: relu(linear)
    float* sums = ws + 1048576;          // 256: [sum | sumsq] per feature

    k_norm_copy  <<<2048, 256, 0, stream>>>((const float4*)e, (float4*)out_e, w);
    k_softmax_agg<<<NBI,  256, 0, stream>>>(w, h, x);
    k_linear     <<<NBI,  128, 0, stream>>>(x, W, bias, y);
    k_stats      <<<DD,   256, 0, stream>>>(y, sums);
    k_bn         <<<(NBI * DD + 255) / 256, 256, 0, stream>>>(y, h, sums, gamma, beta, out_h);
}

// Round 3
// 469.126 us; speedup vs baseline: 1.0425x; 1.0425x over previous
//
#include <hip/hip_runtime.h>

// Problem: h (8,256,128), e (8,256,256,128), all fp32.
// out0 = BN(relu((h+agg)W^T+b))*gamma+beta + h ; out1 = e (copy).
#define BB 8
#define NN 256
#define DD 128
#define NBI   (BB * NN)                 // 2048 (b,i) rows

typedef float f32x4 __attribute__((ext_vector_type(4)));

// ws layout (floats)
#define WS_Y     0               // 262144 : y = relu(linear)
#define WS_WT    262144          // 16384  : W transposed [d][k]
#define WS_P1    278528          // 8192   : stats partial sums  (64 x 128)
#define WS_P2    286720          // 8192   : stats partial sumsq (64 x 128)
#define WS_SCALE 294912          // 128    : gamma * rsqrt(var+eps)
#define WS_SHIFT 295040          // 128    : beta - mean*scale

// ---------------------------------------------------------------------------
// K0: transpose W (128x128, 64 KB) -> Wt[d][k]. One-time, tiny.
// ---------------------------------------------------------------------------
__global__ __launch_bounds__(256) void k_transpose(const float* __restrict__ W,
                                                   float* __restrict__ Wt) {
    for (int idx = threadIdx.x + blockIdx.x * 256; idx < DD * DD; idx += 256 * 8) {
        const int k = idx >> 7, d = idx & 127;
        Wt[d * DD + k] = W[idx];
    }
}

// ---------------------------------------------------------------------------
// K1 (the kernel): one block per (b,i).
//   phase 1: stream e[b,i,:,:] (128 KB): copy -> out_e, per-j sum-of-squares
//   phase 2: softmax over j of sqrt(ssq)
//   phase 3: agg = sum_j p[j] * h[b,j,:];  x = h[b,i,:] + agg   (LDS)
//   phase 4: y[k] = relu(bias[k] + sum_d x[d] * Wt[d][k])       (coalesced W)
// All small compute is hidden under the 512 MB HBM stream.
// ---------------------------------------------------------------------------
__global__ __launch_bounds__(256) void k_fused(const f32x4* __restrict__ e,
                                               f32x4* __restrict__ eo,
                                               const float* __restrict__ h,
                                               const float* __restrict__ Wt,
                                               const float* __restrict__ bias,
                                               float* __restrict__ y) {
    const int bi  = blockIdx.x;          // b*256 + i
    const int b   = bi >> 8;
    const int tid = threadIdx.x;

    __shared__ float sw[NN];     // ssq, then softmax p
    __shared__ float red[8];
    __shared__ float xs[DD];     // h + agg
    __shared__ float acc2[DD];   // cross-half partials

    // ---- phase 1: stream the e slab (8192 float4), copy + row ssq ----
    const long slab = (long)bi * 8192;
    const int  q    = tid & 31;          // float4 slot within a j-row
    #pragma unroll 4
    for (int it = 0; it < 32; ++it) {
        const int f = it * 256 + tid;    // f>>5 = j row (8 rows per iter)
        f32x4 v = __builtin_nontemporal_load(&e[slab + f]);
        __builtin_nontemporal_store(v, &eo[slab + f]);
        float s = v.x * v.x + v.y * v.y + v.z * v.z + v.w * v.w;
        #pragma unroll
        for (int m = 16; m >= 1; m >>= 1) s += __shfl_xor(s, m, 64);
        if (q == 0) sw[f >> 5] = s;
    }
    __syncthreads();

    // ---- phase 2: softmax over j (thread tid owns j = tid) ----
    const int wid = tid >> 6, lane = tid & 63;
    float v = sqrtf(sw[tid]);
    float m = v;
    #pragma unroll
    for (int msk = 32; msk >= 1; msk >>= 1) m = fmaxf(m, __shfl_xor(m, msk, 64));
    if (lane == 0) red[wid] = m;
    __syncthreads();
    m = fmaxf(fmaxf(red[0], red[1]), fmaxf(red[2], red[3]));
    float ev = __expf(v - m);
    float s = ev;
    #pragma unroll
    for (int msk = 32; msk >= 1; msk >>= 1) s += __shfl_xor(s, msk, 64);
    if (lane == 0) red[4 + wid] = s;
    __syncthreads();
    s = (red[4] + red[5]) + (red[6] + red[7]);
    sw[tid] = ev / s;                    // overwrite ssq with p (own slot only)
    __syncthreads();

    // ---- phase 3: agg over j (two thread-halves split the j range) ----
    const int d  = tid & 127;
    const int j0 = (tid >> 7) << 7;      // 0 or 128
    const float* hb = h + ((long)b * NN + j0) * DD + d;
    float acc = 0.f;
    #pragma unroll 8
    for (int j = 0; j < 128; ++j) acc += sw[j0 + j] * hb[(long)j * DD];
    if (tid >= 128) acc2[d] = acc;
    __syncthreads();
    if (tid < 128) {
        xs[d] = h[(long)bi * DD + d] + acc + acc2[d];
    }
    __syncthreads();

    // ---- phase 4: linear + relu (two thread-halves split the d range) ----
    const int k  = tid & 127;
    const int d0 = (tid >> 7) << 6;      // 0 or 64
    float la = 0.f;
    #pragma unroll 8
    for (int dd = 0; dd < 64; ++dd) {
        const int di = d0 + dd;
        la += xs[di] * Wt[di * DD + k];  // lanes vary k -> coalesced
    }
    if (tid >= 128) acc2[k] = la;
    __syncthreads();
    if (tid < 128) {
        float yv = fmaxf(la + acc2[k] + bias[k], 0.f);
        y[(long)bi * DD + k] = yv;
    }
}

// ---------------------------------------------------------------------------
// K2: BN stats stage A — 64 blocks x 32 rows, coalesced, deterministic.
// ---------------------------------------------------------------------------
__global__ __launch_bounds__(256) void k_stats_a(const float* __restrict__ y,
                                                 float* __restrict__ p1,
                                                 float* __restrict__ p2) {
    const int d  = threadIdx.x & 127;
    const int rh = threadIdx.x >> 7;
    const int r0 = blockIdx.x * 32;
    float s = 0.f, s2 = 0.f;
    #pragma unroll 4
    for (int rr = rh; rr < 32; rr += 2) {
        float vv = y[(long)(r0 + rr) * DD + d];
        s += vv; s2 += vv * vv;
    }
    __shared__ float ls[256], ls2[256];
    ls[threadIdx.x] = s; ls2[threadIdx.x] = s2;
    __syncthreads();
    if (threadIdx.x < 128) {
        p1[blockIdx.x * DD + d] = ls[d] + ls[d + 128];
        p2[blockIdx.x * DD + d] = ls2[d] + ls2[d + 128];
    }
}

// ---------------------------------------------------------------------------
// K3: BN stats stage B — finalize scale/shift per feature. 1 block.
// ---------------------------------------------------------------------------
__global__ __launch_bounds__(128) void k_stats_b(const float* __restrict__ p1,
                                                 const float* __restrict__ p2,
                                                 const float* __restrict__ gamma,
                                                 const float* __restrict__ beta,
                                                 float* __restrict__ scale,
                                                 float* __restrict__ shift) {
    const int d = threadIdx.x;
    float s = 0.f, s2 = 0.f;
    #pragma unroll 8
    for (int bb = 0; bb < 64; ++bb) {
        s  += p1[bb * DD + d];
        s2 += p2[bb * DD + d];
    }
    const float inv_n = 1.f / (float)NBI;
    float mean = s * inv_n;
    float var  = s2 * inv_n - mean * mean;
    float inv  = rsqrtf(var + 1e-5f);
    float sc   = gamma[d] * inv;
    scale[d] = sc;
    shift[d] = beta[d] - mean * sc;
}

// ---------------------------------------------------------------------------
// K4: apply BN + residual, float4. out = y*scale + shift + h
// ---------------------------------------------------------------------------
__global__ __launch_bounds__(256) void k_apply(const f32x4* __restrict__ y,
                                               const f32x4* __restrict__ h,
                                               const f32x4* __restrict__ scale,
                                               const f32x4* __restrict__ shift,
                                               f32x4* __restrict__ out) {
    const int i = blockIdx.x * 256 + threadIdx.x;   // 65536 float4 total
    const int c = i & 31;                           // float4 column within row
    f32x4 yv = y[i], hv = h[i], sc = scale[c], sh = shift[c];
    out[i] = yv * sc + sh + hv;
}

extern "C" void kernel_launch(void* const* d_in, const int* in_sizes, int n_in,
                              void* d_out, int out_size, void* d_ws, size_t ws_size,
                              hipStream_t stream) {
    const float* h     = (const float*)d_in[0];
    const float* e     = (const float*)d_in[1];
    const float* W     = (const float*)d_in[2];
    const float* bias  = (const float*)d_in[3];
    const float* gamma = (const float*)d_in[4];
    const float* beta  = (const float*)d_in[5];

    float* out_h = (float*)d_out;                   // (8,256,128)
    float* out_e = out_h + (long)NBI * DD;          // (8,256,256,128)

    float* ws    = (float*)d_ws;
    float* y     = ws + WS_Y;
    float* Wt    = ws + WS_WT;
    float* p1    = ws + WS_P1;
    float* p2    = ws + WS_P2;
    float* scale = ws + WS_SCALE;
    float* shift = ws + WS_SHIFT;

    k_transpose<<<8,    256, 0, stream>>>(W, Wt);
    k_fused    <<<NBI,  256, 0, stream>>>((const f32x4*)e, (f32x4*)out_e, h,
                                          Wt, bias, y);
    k_stats_a  <<<64,   256, 0, stream>>>(y, p1, p2);
    k_stats_b  <<<1,    128, 0, stream>>>(p1, p2, gamma, beta, scale, shift);
    k_apply    <<<256,  256, 0, stream>>>((const f32x4*)y, (const f32x4*)h,
                                          (const f32x4*)scale, (const f32x4*)shift,
                                          (f32x4*)out_h);
}